// Round 4
// baseline (729.066 us; speedup 1.0000x reference)
//
#include <hip/hip_runtime.h>
#include <math.h>

#define D_MODEL 2816
#define N_EXP   64
#define TOPK    8
#define T_TILE  64
#define DC      32
#define NCHUNK  88                  // 2816 / 32
#define SROW    34                  // doubles per LDS row (32 data + 2 pad)
#define SMEM_BYTES 35072

// LDS layout:
//   GEMM phase : xs = [0, 17408)  double[64][34]
//                ws = [17408, 34816) double[64][34]   (scale-folded W)
//   epilogue   : raw  = [0, 32768)      double[64][64]  (raw fp64 logits)
//                ssqp = [32768, 34816)  float[64][8]    (ssq partials)
//                rn   = [34816, 35072)  float[64]       (rsqrt(ssq + D*eps))

__global__ __launch_bounds__(256, 2)
void router_fused(const float* __restrict__ x,
                  const float* __restrict__ W,
                  const float* __restrict__ scale,
                  const float* __restrict__ pes,
                  float* __restrict__ out)
{
    __shared__ __align__(16) char smem[SMEM_BYTES];
    double (*xs)[SROW] = (double (*)[SROW])(smem);
    double (*ws)[SROW] = (double (*)[SROW])(smem + 64 * SROW * 8);
    double* raw  = (double*)smem;
    float*  ssqp = (float*)(smem + 32768);
    float*  rn   = (float*)(smem + 34816);

    const int tid  = threadIdx.x;
    const int tb   = blockIdx.x * T_TILE;
    const int lrow = tid >> 3;          // 0..31  (loader row)
    const int kk   = tid & 7;           // 0..7   (loader d-quad)
    const int tg4  = (tid >> 4) << 2;   // compute: token base (4 consecutive)
    const int eg   = tid & 15;          // compute: expert base (strided by 16)

    double acc[4][4] = {};
    float ssq2[2] = {0.f, 0.f};

    for (int c = 0; c < NCHUNK; ++c) {
        const int d0 = c * DC;
        float4 xg[2], wg[2];
        const float4 sc4 = *(const float4*)(scale + d0 + kk * 4);
        #pragma unroll
        for (int r = 0; r < 2; ++r) {
            const int row = r * 32 + lrow;
            xg[r] = *(const float4*)(x + (size_t)(tb + row) * D_MODEL + d0 + kk * 4);
            wg[r] = *(const float4*)(W + (size_t)row * D_MODEL + d0 + kk * 4);
        }
        __syncthreads();   // previous chunk's compute done
        #pragma unroll
        for (int r = 0; r < 2; ++r) {
            const int row = r * 32 + lrow;
            ssq2[r] += xg[r].x * xg[r].x + xg[r].y * xg[r].y
                     + xg[r].z * xg[r].z + xg[r].w * xg[r].w;
            double2* xrow = (double2*)&xs[row][kk * 4];
            xrow[0] = make_double2((double)xg[r].x, (double)xg[r].y);
            xrow[1] = make_double2((double)xg[r].z, (double)xg[r].w);
            double2* wrow = (double2*)&ws[row][kk * 4];
            wrow[0] = make_double2((double)wg[r].x * (double)sc4.x,
                                   (double)wg[r].y * (double)sc4.y);
            wrow[1] = make_double2((double)wg[r].z * (double)sc4.z,
                                   (double)wg[r].w * (double)sc4.w);
        }
        __syncthreads();   // tiles ready
        #pragma unroll 2
        for (int d = 0; d < DC; d += 2) {
            double2 xf[4], wf[4];
            #pragma unroll
            for (int u = 0; u < 4; ++u)
                xf[u] = *(const double2*)&xs[tg4 + u][d];
            #pragma unroll
            for (int v = 0; v < 4; ++v)
                wf[v] = *(const double2*)&ws[eg + 16 * v][d];
            #pragma unroll
            for (int u = 0; u < 4; ++u)
                #pragma unroll
                for (int v = 0; v < 4; ++v) {
                    acc[u][v] = fma(xf[u].x, wf[v].x, acc[u][v]);
                    acc[u][v] = fma(xf[u].y, wf[v].y, acc[u][v]);
                }
        }
    }

    __syncthreads();   // last chunk's compute done everywhere; tiles now dead

    // write raw fp64 logits + ssq partials
    #pragma unroll
    for (int u = 0; u < 4; ++u)
        #pragma unroll
        for (int v = 0; v < 4; ++v)
            raw[(tg4 + u) * 64 + (eg + 16 * v)] = acc[u][v];
    ssqp[lrow * 8 + kk]        = ssq2[0];
    ssqp[(32 + lrow) * 8 + kk] = ssq2[1];
    __syncthreads();

    if (tid < 64) {
        float s = 0.f;
        #pragma unroll
        for (int j = 0; j < 8; ++j) s += ssqp[tid * 8 + j];
        // scores = raw * rsqrt(ssq + D*eps)   (== raw * rsqrt(mean+eps) * D^-1/2)
        float v  = s + 0.002816f;
        float r0 = rsqrtf(v);
        r0 = r0 * (1.5f - 0.5f * v * r0 * r0);   // NR refinement
        rn[tid] = r0;
    }
    __syncthreads();

    // top-k + softmax-renorm + scatter; wave w handles tokens [w*16, w*16+16)
    const int wv = tid >> 6, lane = tid & 63;
    const float pl = pes[lane];
    for (int tk = 0; tk < 16; ++tk) {
        const int t = wv * 16 + tk;
        const double sraw = raw[t * 64 + lane];
        double m = sraw;
        #pragma unroll
        for (int off = 32; off > 0; off >>= 1) {
            double o = __shfl_xor(m, off);
            m = m > o ? m : o;
        }
        int rank = 0;
        for (int j = 0; j < 64; ++j) {
            double sj = raw[t * 64 + j];
            rank += (sj > sraw) || (sj == sraw && j < lane);
        }
        const bool sel = rank < TOPK;
        const float rt = rn[t];
        float ex = sel ? __expf((float)(sraw - m) * rt) : 0.f;
        float sum = ex;
        #pragma unroll
        for (int off = 32; off > 0; off >>= 1) sum += __shfl_xor(sum, off);
        out[(size_t)(tb + t) * N_EXP + lane] = sel ? (ex / sum) * pl : 0.f;
    }
}

extern "C" void kernel_launch(void* const* d_in, const int* in_sizes, int n_in,
                              void* d_out, int out_size, void* d_ws, size_t ws_size,
                              hipStream_t stream) {
    const float* x     = (const float*)d_in[0];
    const float* W     = (const float*)d_in[1];
    const float* scale = (const float*)d_in[2];
    const float* pes   = (const float*)d_in[3];
    float* out = (float*)d_out;

    const int ntok    = in_sizes[0] / D_MODEL;   // 32768
    const int nblocks = ntok / T_TILE;           // 512
    router_fused<<<dim3(nblocks), dim3(256), 0, stream>>>(x, W, scale, pes, out);
}